// Round 17
// baseline (146.496 us; speedup 1.0000x reference)
//
#include <hip/hip_runtime.h>

// GraphGCN R16: R14 core (unroll-4 gather, VGPR~28) + D-half bucket split.
//   R15 lesson: unroll-8 raised VGPR 28->44, occ 46->30%, agg +20% — never
//   trade TLP for ILP when latency-bound. R14's occ 46% was achieved (grid
//   782 = 3/CU + imbalance), not resource-capped -> raise grid instead:
//   2 blocks/bucket, each owns a 64B half of every row (4-lane groups).
//   Grid 1564 = 6.1/CU; halves land on disjoint XCD sets under round-robin
//   dispatch -> per-XCD gather working set halves (12.8->6.4MB).

#define BNODES   128
#define NBUCKMAX 1024     // supports N <= 131072
#define CBLOCKS  1024     // bucket edge chunks
#define CONVB    1024     // convert blocks inside bucket kernel
#define LDSCAP   1664     // per-chunk LDS edge capacity (per = E/CBLOCKS = 1563)
#define SLOTS    8
#define CAP8     384      // per-(slot,bucket) capacity (mean 256, +8 sigma)
#define LISTCAP  (SLOTS * CAP8)   // 3072 >= max combined bucket size

typedef float v4f __attribute__((ext_vector_type(4)));
typedef unsigned int v4u __attribute__((ext_vector_type(4)));
typedef unsigned short v4h __attribute__((ext_vector_type(4)));

__device__ __forceinline__ unsigned short benc(float f) {
    union { float f; unsigned u; } x;
    x.f = f;
    unsigned u = x.u;
    return (unsigned short)((u + 0x7FFFu + ((u >> 16) & 1u)) >> 16);  // RN-even
}
__device__ __forceinline__ float f_lo(unsigned u) {   // bf16 in low ushort
    union { unsigned u; float f; } x; x.u = u << 16; return x.f;
}
__device__ __forceinline__ float f_hi(unsigned u) {   // bf16 in high ushort
    union { unsigned u; float f; } x; x.u = u & 0xFFFF0000u; return x.f;
}

// 4-lane-group gather-accumulate over LDS edge list [nb,ne); lane owns 16B
// of a 64B half-row at ushort offset hoff. Unroll-4 (R14-proven: VGPR~28).
__device__ __forceinline__ void gather_acc(const unsigned short* __restrict__ xin,
                                           const unsigned int* list,
                                           int nb, int ne, int hoff, float* a) {
    int k = nb;
    for (; k + 4 <= ne; k += 4) {
        int s0 = (int)list[k + 0];
        int s1 = (int)list[k + 1];
        int s2 = (int)list[k + 2];
        int s3 = (int)list[k + 3];
        const uint4 u0 = *reinterpret_cast<const uint4*>(xin + ((size_t)s0 << 6) + hoff);
        const uint4 u1 = *reinterpret_cast<const uint4*>(xin + ((size_t)s1 << 6) + hoff);
        const uint4 u2 = *reinterpret_cast<const uint4*>(xin + ((size_t)s2 << 6) + hoff);
        const uint4 u3 = *reinterpret_cast<const uint4*>(xin + ((size_t)s3 << 6) + hoff);
        a[0] += f_lo(u0.x) + f_lo(u1.x) + f_lo(u2.x) + f_lo(u3.x);
        a[1] += f_hi(u0.x) + f_hi(u1.x) + f_hi(u2.x) + f_hi(u3.x);
        a[2] += f_lo(u0.y) + f_lo(u1.y) + f_lo(u2.y) + f_lo(u3.y);
        a[3] += f_hi(u0.y) + f_hi(u1.y) + f_hi(u2.y) + f_hi(u3.y);
        a[4] += f_lo(u0.z) + f_lo(u1.z) + f_lo(u2.z) + f_lo(u3.z);
        a[5] += f_hi(u0.z) + f_hi(u1.z) + f_hi(u2.z) + f_hi(u3.z);
        a[6] += f_lo(u0.w) + f_lo(u1.w) + f_lo(u2.w) + f_lo(u3.w);
        a[7] += f_hi(u0.w) + f_hi(u1.w) + f_hi(u2.w) + f_hi(u3.w);
    }
    for (; k < ne; ++k) {
        int s = (int)list[k];
        const uint4 u = *reinterpret_cast<const uint4*>(xin + ((size_t)s << 6) + hoff);
        a[0] += f_lo(u.x); a[1] += f_hi(u.x);
        a[2] += f_lo(u.y); a[3] += f_hi(u.y);
        a[4] += f_lo(u.z); a[5] += f_hi(u.z);
        a[6] += f_lo(u.w); a[7] += f_hi(u.w);
    }
}

__global__ void zero_kernel(int* __restrict__ p, int n) {
    int stride = gridDim.x * blockDim.x;
    for (int i = blockIdx.x * blockDim.x + threadIdx.x; i < n; i += stride) p[i] = 0;
}

// blocks [0,CONVB): f32->bf16 convert. blocks [CONVB,CONVB+CBLOCKS): bucket.
__global__ void bucket_kernel(const float* __restrict__ feat,
                              unsigned short* __restrict__ feat_h, int total4,
                              const int* __restrict__ src, const int* __restrict__ dst,
                              int E, int nbuck,
                              int* __restrict__ gcur,
                              unsigned int* __restrict__ recs) {
    __shared__ unsigned int lrec[LDSCAP];
    __shared__ unsigned short lb[LDSCAP];
    __shared__ int hist[NBUCKMAX];
    __shared__ int cur[NBUCKMAX];
    if (blockIdx.x < CONVB) {
        int stride = CONVB * blockDim.x;
        for (int t = blockIdx.x * blockDim.x + threadIdx.x; t < total4; t += stride) {
            const float4 v = *reinterpret_cast<const float4*>(feat + (size_t)t * 4);
            v4h h;
            h.x = benc(v.x); h.y = benc(v.y); h.z = benc(v.z); h.w = benc(v.w);
            __builtin_nontemporal_store(h, reinterpret_cast<v4h*>(feat_h + (size_t)t * 4));
        }
        return;
    }
    int cb = blockIdx.x - CONVB;
    int slot = cb & (SLOTS - 1);
    int* gslot = gcur + (size_t)slot * nbuck;
    unsigned int* rslot = recs + (size_t)slot * nbuck * CAP8;
    int per = (E + CBLOCKS - 1) / CBLOCKS;
    int beg = cb * per;
    int end = min(E, beg + per);
    for (int cs = beg; cs < end; cs += LDSCAP) {
        int m = min(end - cs, LDSCAP);
        for (int i = threadIdx.x; i < nbuck; i += blockDim.x) hist[i] = 0;
        __syncthreads();
        // pass A: read edges once, pack into LDS, histogram
        for (int i = threadIdx.x; i < m; i += blockDim.x) {
            int d = dst[cs + i];
            int s = src[cs + i];
            int b = d >> 7;
            lrec[i] = ((unsigned)s << 7) | (unsigned)(d & 127);
            lb[i] = (unsigned short)b;
            atomicAdd(&hist[b], 1);
        }
        __syncthreads();
        // reserve contiguous windows in this block's slot
        for (int i = threadIdx.x; i < nbuck; i += blockDim.x) {
            int h = hist[i];
            cur[i] = h ? atomicAdd(&gslot[i], h) : 0;
        }
        __syncthreads();
        // pass B: scatter from LDS into slot-local window
        for (int i = threadIdx.x; i < m; i += blockDim.x) {
            int b = lb[i];
            int pos = atomicAdd(&cur[b], 1);   // LDS cursor holds slot base
            if (pos < CAP8)
                rslot[(size_t)b * CAP8 + pos] = lrec[i];
        }
        __syncthreads();
    }
}

// Two blocks per bucket: bucket = blockIdx>>1, half = blockIdx&1.
// Each block drains the bucket's 8 slot windows, LDS counting-sorts by local
// dst, then work-stealing 4-lane-group gather over its 64B half of each row.
// FINAL=0: gathers feat_h -> buf_xh (bf16).  FINAL=1: gathers buf_xh,
// fuses out = (x + mean2)*0.5 -> f32.
template <int FINAL>
__launch_bounds__(512)
__global__ void agg_kernel(const unsigned int* __restrict__ recs,
                           const int* __restrict__ gcur,
                           const unsigned short* __restrict__ xin,
                           unsigned short* __restrict__ outh,
                           float* __restrict__ outf, int N, int nbuck) {
    __shared__ unsigned int list[LISTCAP];
    __shared__ int hist[BNODES], cur[BNODES], offl[BNODES + 1];
    __shared__ int cnts[SLOTS];
    __shared__ int ticket;
    int b = blockIdx.x >> 1;
    int half = blockIdx.x & 1;
    int tid = threadIdx.x;
    int lo = b << 7;
    if (tid < BNODES) hist[tid] = 0;
    if (tid < SLOTS) cnts[tid] = min(gcur[(size_t)tid * nbuck + b], CAP8);
    if (tid == 0) ticket = 0;
    __syncthreads();
    int num = 0;
#pragma unroll
    for (int s = 0; s < SLOTS; ++s) {
        const unsigned int* w = recs + ((size_t)s * nbuck + b) * CAP8;
        int cs = cnts[s];
        for (int k = tid; k < cs; k += 512)
            atomicAdd(&hist[w[k] & 127], 1);
        num += cs;
    }
    __syncthreads();
    if (tid < BNODES) cur[tid] = hist[tid];
    __syncthreads();
#pragma unroll
    for (int s = 1; s < BNODES; s <<= 1) {
        int v = (tid < BNODES && tid >= s) ? cur[tid - s] : 0;
        __syncthreads();
        if (tid < BNODES) cur[tid] += v;
        __syncthreads();
    }
    if (tid < BNODES) {
        int excl = tid ? cur[tid - 1] : 0;
        offl[tid] = excl;
    }
    if (tid == 0) offl[BNODES] = num;
    __syncthreads();
    if (tid < BNODES) cur[tid] = offl[tid];   // cursors = exclusive scan
    __syncthreads();
#pragma unroll
    for (int s = 0; s < SLOTS; ++s) {
        const unsigned int* w = recs + ((size_t)s * nbuck + b) * CAP8;
        int cs = cnts[s];
        for (int k = tid; k < cs; k += 512) {
            unsigned rec = w[k];
            int pos = atomicAdd(&cur[rec & 127], 1);
            list[pos] = rec >> 7;
        }
    }
    __syncthreads();
    int nrows = min(BNODES, N - lo);
    int c = tid & 3;                 // 4 lanes per row-half
    int hoff = half * 32 + c * 8;    // ushort offset within the 64-elem row
    while (true) {
        int r = 0;
        if (c == 0) r = atomicAdd(&ticket, 1);
        r = __shfl(r, 0, 4);
        if (r >= nrows) break;
        int node = lo + r;
        int nb = offl[r];
        int ne = offl[r + 1];
        float a[8];
#pragma unroll
        for (int j = 0; j < 8; ++j) a[j] = 0.f;
        gather_acc(xin, list, nb, ne, hoff, a);
        float inv = (ne > nb) ? 1.0f / (float)(ne - nb) : 0.0f;
#pragma unroll
        for (int j = 0; j < 8; ++j) a[j] *= inv;
        if (FINAL) {
            const uint4 us = *reinterpret_cast<const uint4*>(xin + ((size_t)node << 6) + hoff);
            v4f r0, r1;
            r0.x = (f_lo(us.x) + a[0]) * 0.5f;
            r0.y = (f_hi(us.x) + a[1]) * 0.5f;
            r0.z = (f_lo(us.y) + a[2]) * 0.5f;
            r0.w = (f_hi(us.y) + a[3]) * 0.5f;
            r1.x = (f_lo(us.z) + a[4]) * 0.5f;
            r1.y = (f_hi(us.z) + a[5]) * 0.5f;
            r1.z = (f_lo(us.w) + a[6]) * 0.5f;
            r1.w = (f_hi(us.w) + a[7]) * 0.5f;
            float* op = outf + ((size_t)node << 6) + hoff;
            __builtin_nontemporal_store(r0, reinterpret_cast<v4f*>(op));
            __builtin_nontemporal_store(r1, reinterpret_cast<v4f*>(op + 4));
        } else {
            v4u h;
            h.x = (unsigned)benc(a[0]) | ((unsigned)benc(a[1]) << 16);
            h.y = (unsigned)benc(a[2]) | ((unsigned)benc(a[3]) << 16);
            h.z = (unsigned)benc(a[4]) | ((unsigned)benc(a[5]) << 16);
            h.w = (unsigned)benc(a[6]) | ((unsigned)benc(a[7]) << 16);
            __builtin_nontemporal_store(h, reinterpret_cast<v4u*>(outh + ((size_t)node << 6) + hoff));
        }
    }
}

static inline size_t align_up(size_t x, size_t a) { return (x + a - 1) & ~(a - 1); }

extern "C" void kernel_launch(void* const* d_in, const int* in_sizes, int n_in,
                              void* d_out, int out_size, void* d_ws, size_t ws_size,
                              hipStream_t stream) {
    const float* feat = (const float*)d_in[0];
    const int*   src  = (const int*)d_in[1];
    const int*   dst  = (const int*)d_in[2];
    float* out = (float*)d_out;

    const int D = 64;
    int N = in_sizes[0] / D;                // 100000
    int E = in_sizes[1];                    // 1600000
    int nbuck = (N + BNODES - 1) / BNODES;  // 782

    // workspace: feat_h 12.8MB + buf_xh 12.8MB + recs 8*782*384*4 = 9.6MB
    char* ws = (char*)d_ws;
    size_t off = 0;
    unsigned short* feat_h = (unsigned short*)(ws + off); off = align_up(off + (size_t)N * D * sizeof(unsigned short), 256);
    unsigned short* buf_xh = (unsigned short*)(ws + off); off = align_up(off + (size_t)N * D * sizeof(unsigned short), 256);
    unsigned int* recs = (unsigned int*)(ws + off); off = align_up(off + (size_t)SLOTS * nbuck * CAP8 * sizeof(unsigned int), 256);
    int* gcur = (int*)(ws + off); off = align_up(off + (size_t)SLOTS * nbuck * sizeof(int), 256);
    (void)ws_size;

    zero_kernel<<<8, 1024, 0, stream>>>(gcur, SLOTS * nbuck);
    bucket_kernel<<<CONVB + CBLOCKS, 256, 0, stream>>>(feat, feat_h, N * D / 4,
                                                       src, dst, E, nbuck, gcur, recs);
    agg_kernel<0><<<2 * nbuck, 512, 0, stream>>>(recs, gcur, feat_h, buf_xh, nullptr, N, nbuck);
    agg_kernel<1><<<2 * nbuck, 512, 0, stream>>>(recs, gcur, buf_xh, nullptr, out, N, nbuck);
}

// Round 18
// 105.093 us; speedup vs baseline: 1.3940x; 1.3940x over previous
//
#include <hip/hip_runtime.h>

// GraphGCN R17: revert to R14 (best: 106.4us) + LDS-staged agg sort.
//   R16 lesson: L2 fill granule is 128B — D-half split across XCDs doubled
//   HBM fill (FETCH 79->155MB). Gather passes are pinned at ~42us across
//   structures (R7/R9/R14: occupancy 38-58%, ILP 4-8) = random-access
//   request-throughput ceiling (~3.2M line-requests/pass, 4.8TB/s demand).
//   R17 trim: agg copies its 8 slot windows into LDS once (coalesced);
//   hist + sort-scatter then run from LDS (R14 read global windows twice).

#define BNODES   128
#define NBUCKMAX 1024     // supports N <= 131072
#define CBLOCKS  1024     // bucket edge chunks
#define CONVB    1024     // convert blocks inside bucket kernel
#define LDSCAP   1664     // per-chunk LDS edge capacity (per = E/CBLOCKS = 1563)
#define SLOTS    8
#define CAP8     384      // per-(slot,bucket) capacity (mean 256, +8 sigma)
#define LISTCAP  (SLOTS * CAP8)   // 3072 >= max combined bucket size

typedef float v4f __attribute__((ext_vector_type(4)));
typedef unsigned int v4u __attribute__((ext_vector_type(4)));
typedef unsigned short v4h __attribute__((ext_vector_type(4)));

__device__ __forceinline__ unsigned short benc(float f) {
    union { float f; unsigned u; } x;
    x.f = f;
    unsigned u = x.u;
    return (unsigned short)((u + 0x7FFFu + ((u >> 16) & 1u)) >> 16);  // RN-even
}
__device__ __forceinline__ float f_lo(unsigned u) {   // bf16 in low ushort
    union { unsigned u; float f; } x; x.u = u << 16; return x.f;
}
__device__ __forceinline__ float f_hi(unsigned u) {   // bf16 in high ushort
    union { unsigned u; float f; } x; x.u = u & 0xFFFF0000u; return x.f;
}

// 8-lane-group gather-accumulate over LDS edge list [nb,ne); lane owns 16B.
// Unroll-4 (R14-proven: VGPR~28; R15 showed unroll-8 costs occupancy).
__device__ __forceinline__ void gather_acc(const unsigned short* __restrict__ xin,
                                           const unsigned int* list,
                                           int nb, int ne, int c, float* a) {
    int k = nb;
    for (; k + 4 <= ne; k += 4) {
        int s0 = (int)list[k + 0];
        int s1 = (int)list[k + 1];
        int s2 = (int)list[k + 2];
        int s3 = (int)list[k + 3];
        const uint4 u0 = *reinterpret_cast<const uint4*>(xin + ((size_t)s0 << 6) + c * 8);
        const uint4 u1 = *reinterpret_cast<const uint4*>(xin + ((size_t)s1 << 6) + c * 8);
        const uint4 u2 = *reinterpret_cast<const uint4*>(xin + ((size_t)s2 << 6) + c * 8);
        const uint4 u3 = *reinterpret_cast<const uint4*>(xin + ((size_t)s3 << 6) + c * 8);
        a[0] += f_lo(u0.x) + f_lo(u1.x) + f_lo(u2.x) + f_lo(u3.x);
        a[1] += f_hi(u0.x) + f_hi(u1.x) + f_hi(u2.x) + f_hi(u3.x);
        a[2] += f_lo(u0.y) + f_lo(u1.y) + f_lo(u2.y) + f_lo(u3.y);
        a[3] += f_hi(u0.y) + f_hi(u1.y) + f_hi(u2.y) + f_hi(u3.y);
        a[4] += f_lo(u0.z) + f_lo(u1.z) + f_lo(u2.z) + f_lo(u3.z);
        a[5] += f_hi(u0.z) + f_hi(u1.z) + f_hi(u2.z) + f_hi(u3.z);
        a[6] += f_lo(u0.w) + f_lo(u1.w) + f_lo(u2.w) + f_lo(u3.w);
        a[7] += f_hi(u0.w) + f_hi(u1.w) + f_hi(u2.w) + f_hi(u3.w);
    }
    for (; k < ne; ++k) {
        int s = (int)list[k];
        const uint4 u = *reinterpret_cast<const uint4*>(xin + ((size_t)s << 6) + c * 8);
        a[0] += f_lo(u.x); a[1] += f_hi(u.x);
        a[2] += f_lo(u.y); a[3] += f_hi(u.y);
        a[4] += f_lo(u.z); a[5] += f_hi(u.z);
        a[6] += f_lo(u.w); a[7] += f_hi(u.w);
    }
}

__global__ void zero_kernel(int* __restrict__ p, int n) {
    int stride = gridDim.x * blockDim.x;
    for (int i = blockIdx.x * blockDim.x + threadIdx.x; i < n; i += stride) p[i] = 0;
}

// blocks [0,CONVB): f32->bf16 convert. blocks [CONVB,CONVB+CBLOCKS): bucket.
__global__ void bucket_kernel(const float* __restrict__ feat,
                              unsigned short* __restrict__ feat_h, int total4,
                              const int* __restrict__ src, const int* __restrict__ dst,
                              int E, int nbuck,
                              int* __restrict__ gcur,
                              unsigned int* __restrict__ recs) {
    __shared__ unsigned int lrec[LDSCAP];
    __shared__ unsigned short lb[LDSCAP];
    __shared__ int hist[NBUCKMAX];
    __shared__ int cur[NBUCKMAX];
    if (blockIdx.x < CONVB) {
        int stride = CONVB * blockDim.x;
        for (int t = blockIdx.x * blockDim.x + threadIdx.x; t < total4; t += stride) {
            const float4 v = *reinterpret_cast<const float4*>(feat + (size_t)t * 4);
            v4h h;
            h.x = benc(v.x); h.y = benc(v.y); h.z = benc(v.z); h.w = benc(v.w);
            __builtin_nontemporal_store(h, reinterpret_cast<v4h*>(feat_h + (size_t)t * 4));
        }
        return;
    }
    int cb = blockIdx.x - CONVB;
    int slot = cb & (SLOTS - 1);
    int* gslot = gcur + (size_t)slot * nbuck;
    unsigned int* rslot = recs + (size_t)slot * nbuck * CAP8;
    int per = (E + CBLOCKS - 1) / CBLOCKS;
    int beg = cb * per;
    int end = min(E, beg + per);
    for (int cs = beg; cs < end; cs += LDSCAP) {
        int m = min(end - cs, LDSCAP);
        for (int i = threadIdx.x; i < nbuck; i += blockDim.x) hist[i] = 0;
        __syncthreads();
        // pass A: read edges once, pack into LDS, histogram
        for (int i = threadIdx.x; i < m; i += blockDim.x) {
            int d = dst[cs + i];
            int s = src[cs + i];
            int b = d >> 7;
            lrec[i] = ((unsigned)s << 7) | (unsigned)(d & 127);
            lb[i] = (unsigned short)b;
            atomicAdd(&hist[b], 1);
        }
        __syncthreads();
        // reserve contiguous windows in this block's slot
        for (int i = threadIdx.x; i < nbuck; i += blockDim.x) {
            int h = hist[i];
            cur[i] = h ? atomicAdd(&gslot[i], h) : 0;
        }
        __syncthreads();
        // pass B: scatter from LDS into slot-local window
        for (int i = threadIdx.x; i < m; i += blockDim.x) {
            int b = lb[i];
            int pos = atomicAdd(&cur[b], 1);   // LDS cursor holds slot base
            if (pos < CAP8)
                rslot[(size_t)b * CAP8 + pos] = lrec[i];
        }
        __syncthreads();
    }
}

// One bucket per block: stage 8 slot windows into LDS (one coalesced global
// read), LDS counting sort by local dst, then work-stealing 8-lane-group
// gather. FINAL=0: gathers feat_h -> buf_xh (bf16). FINAL=1: gathers buf_xh,
// fuses out = (x + mean2)*0.5 -> f32.
template <int FINAL>
__launch_bounds__(512)
__global__ void agg_kernel(const unsigned int* __restrict__ recs,
                           const int* __restrict__ gcur,
                           const unsigned short* __restrict__ xin,
                           unsigned short* __restrict__ outh,
                           float* __restrict__ outf, int N, int nbuck) {
    __shared__ unsigned int stage[LISTCAP];
    __shared__ unsigned int list[LISTCAP];
    __shared__ int hist[BNODES], cur[BNODES], offl[BNODES + 1];
    __shared__ int cnts[SLOTS];
    __shared__ int ticket;
    int b = blockIdx.x;
    int tid = threadIdx.x;
    int lo = b << 7;
    if (tid < BNODES) hist[tid] = 0;
    if (tid < SLOTS) cnts[tid] = min(gcur[(size_t)tid * nbuck + b], CAP8);
    if (tid == 0) ticket = 0;
    __syncthreads();
    // stage all slot windows into LDS (coalesced, read global ONCE)
    int num = 0;
#pragma unroll
    for (int s = 0; s < SLOTS; ++s) {
        const unsigned int* w = recs + ((size_t)s * nbuck + b) * CAP8;
        int cs = cnts[s];
        for (int k = tid; k < cs; k += 512)
            stage[num + k] = w[k];
        num += cs;
    }
    __syncthreads();
    // histogram from LDS
    for (int k = tid; k < num; k += 512)
        atomicAdd(&hist[stage[k] & 127], 1);
    __syncthreads();
    if (tid < BNODES) cur[tid] = hist[tid];
    __syncthreads();
#pragma unroll
    for (int s = 1; s < BNODES; s <<= 1) {
        int v = (tid < BNODES && tid >= s) ? cur[tid - s] : 0;
        __syncthreads();
        if (tid < BNODES) cur[tid] += v;
        __syncthreads();
    }
    if (tid < BNODES) {
        int excl = tid ? cur[tid - 1] : 0;
        offl[tid] = excl;
    }
    if (tid == 0) offl[BNODES] = num;
    __syncthreads();
    if (tid < BNODES) cur[tid] = offl[tid];   // cursors = exclusive scan
    __syncthreads();
    // scatter (sort) from LDS stage -> list
    for (int k = tid; k < num; k += 512) {
        unsigned rec = stage[k];
        int pos = atomicAdd(&cur[rec & 127], 1);
        list[pos] = rec >> 7;
    }
    __syncthreads();
    int nrows = min(BNODES, N - lo);
    int c = tid & 7;
    while (true) {
        int r = 0;
        if (c == 0) r = atomicAdd(&ticket, 1);
        r = __shfl(r, 0, 8);
        if (r >= nrows) break;
        int node = lo + r;
        int nb = offl[r];
        int ne = offl[r + 1];
        float a[8];
#pragma unroll
        for (int j = 0; j < 8; ++j) a[j] = 0.f;
        gather_acc(xin, list, nb, ne, c, a);
        float inv = (ne > nb) ? 1.0f / (float)(ne - nb) : 0.0f;
#pragma unroll
        for (int j = 0; j < 8; ++j) a[j] *= inv;
        if (FINAL) {
            const uint4 us = *reinterpret_cast<const uint4*>(xin + ((size_t)node << 6) + c * 8);
            v4f r0, r1;
            r0.x = (f_lo(us.x) + a[0]) * 0.5f;
            r0.y = (f_hi(us.x) + a[1]) * 0.5f;
            r0.z = (f_lo(us.y) + a[2]) * 0.5f;
            r0.w = (f_hi(us.y) + a[3]) * 0.5f;
            r1.x = (f_lo(us.z) + a[4]) * 0.5f;
            r1.y = (f_hi(us.z) + a[5]) * 0.5f;
            r1.z = (f_lo(us.w) + a[6]) * 0.5f;
            r1.w = (f_hi(us.w) + a[7]) * 0.5f;
            float* op = outf + ((size_t)node << 6) + c * 8;
            __builtin_nontemporal_store(r0, reinterpret_cast<v4f*>(op));
            __builtin_nontemporal_store(r1, reinterpret_cast<v4f*>(op + 4));
        } else {
            v4u h;
            h.x = (unsigned)benc(a[0]) | ((unsigned)benc(a[1]) << 16);
            h.y = (unsigned)benc(a[2]) | ((unsigned)benc(a[3]) << 16);
            h.z = (unsigned)benc(a[4]) | ((unsigned)benc(a[5]) << 16);
            h.w = (unsigned)benc(a[6]) | ((unsigned)benc(a[7]) << 16);
            __builtin_nontemporal_store(h, reinterpret_cast<v4u*>(outh + ((size_t)node << 6) + c * 8));
        }
    }
}

static inline size_t align_up(size_t x, size_t a) { return (x + a - 1) & ~(a - 1); }

extern "C" void kernel_launch(void* const* d_in, const int* in_sizes, int n_in,
                              void* d_out, int out_size, void* d_ws, size_t ws_size,
                              hipStream_t stream) {
    const float* feat = (const float*)d_in[0];
    const int*   src  = (const int*)d_in[1];
    const int*   dst  = (const int*)d_in[2];
    float* out = (float*)d_out;

    const int D = 64;
    int N = in_sizes[0] / D;                // 100000
    int E = in_sizes[1];                    // 1600000
    int nbuck = (N + BNODES - 1) / BNODES;  // 782

    // workspace: feat_h 12.8MB + buf_xh 12.8MB + recs 8*782*384*4 = 9.6MB
    char* ws = (char*)d_ws;
    size_t off = 0;
    unsigned short* feat_h = (unsigned short*)(ws + off); off = align_up(off + (size_t)N * D * sizeof(unsigned short), 256);
    unsigned short* buf_xh = (unsigned short*)(ws + off); off = align_up(off + (size_t)N * D * sizeof(unsigned short), 256);
    unsigned int* recs = (unsigned int*)(ws + off); off = align_up(off + (size_t)SLOTS * nbuck * CAP8 * sizeof(unsigned int), 256);
    int* gcur = (int*)(ws + off); off = align_up(off + (size_t)SLOTS * nbuck * sizeof(int), 256);
    (void)ws_size;

    zero_kernel<<<8, 1024, 0, stream>>>(gcur, SLOTS * nbuck);
    bucket_kernel<<<CONVB + CBLOCKS, 256, 0, stream>>>(feat, feat_h, N * D / 4,
                                                       src, dst, E, nbuck, gcur, recs);
    agg_kernel<0><<<nbuck, 512, 0, stream>>>(recs, gcur, feat_h, buf_xh, nullptr, N, nbuck);
    agg_kernel<1><<<nbuck, 512, 0, stream>>>(recs, gcur, buf_xh, nullptr, out, N, nbuck);
}